// Round 15
// baseline (544.950 us; speedup 1.0000x reference)
//
#include <hip/hip_runtime.h>
#include <hip/hip_bf16.h>

typedef __attribute__((ext_vector_type(4))) float f32x4;
typedef __attribute__((ext_vector_type(8))) short s16x8;

#define W2P_BYTES   8388608ull                 // 64*256*256 bf16
#define SLAB_FLOATS 1048576ull                 // 4096*256
#define CNT_OFF     (W2P_BYTES + 7ull * SLAB_FLOATS * 4ull)
#define WS_NEEDED   (CNT_OFF + 512ull)         // +128 u32 counters

// ---------------------------------------------------------------------------
// k01: fused weight-pack (blocks 0..511) + f-path select (blocks 512..1023).
// Disjoint block ranges, shared LDS buffer, zero interaction.
// pack: g_fc2_w (64,256,256) fp32 -> bf16 MFMA fragments, 1KB contiguous per
// fragment; frag f = (n*8+ks)*16 + ct: lane l, elem j =
//   g2w[n][ks*32 + (l>>4)*8 + j][ct*16 + (l&15)]
// select: sparse_w (4096,64), 8 rows per block.
// ---------------------------------------------------------------------------
__global__ __launch_bounds__(256) void k01(
    const float* __restrict__ g2w, ushort* __restrict__ out,
    const float* __restrict__ x,
    const float* __restrict__ w1, const float* __restrict__ b1,
    const float* __restrict__ w2, const float* __restrict__ b2,
    const float* __restrict__ wsk, const float* __restrict__ bsk,
    const float* __restrict__ wg, const float* __restrict__ bg,
    const float* __restrict__ lng, const float* __restrict__ lnb,
    float* __restrict__ spw) {
  __shared__ __align__(16) float shbuf[32 * 257];
  const int t = threadIdx.x;
  if (blockIdx.x < 512) {
    // ---------------- pack path ----------------
    float (*tile)[257] = reinterpret_cast<float (*)[257]>(shbuf);
    const int n = blockIdx.x >> 3, ks = blockIdx.x & 7;
    const float* src = g2w + ((size_t)n * 256 + ks * 32) * 256;
    for (int i = t; i < 8192; i += 256)
      tile[i >> 8][i & 255] = src[i];
    __syncthreads();
#pragma unroll
    for (int q = 0; q < 4; ++q) {
      int chunk = q * 256 + t;
      int ct = chunk >> 6, l = chunk & 63;
      int g = l >> 4, cl = l & 15;
      s16x8 pk;
#pragma unroll
      for (int j = 0; j < 8; ++j) {
        __hip_bfloat16 h = __float2bfloat16(tile[g * 8 + j][ct * 16 + cl]);
        pk[j] = *reinterpret_cast<short*>(&h);
      }
      *reinterpret_cast<s16x8*>(out + ((size_t)(n * 8 + ks) * 1024 + chunk) * 8) = pk;
    }
  } else {
    // ---------------- select path ----------------
    float (*xs)[64]  = reinterpret_cast<float (*)[64]>(shbuf);
    float (*t1)[256] = reinterpret_cast<float (*)[256]>(shbuf + 512);
    float (*wvv)[64] = reinterpret_cast<float (*)[64]>(shbuf + 2560);
    const int b0 = (int)(blockIdx.x - 512) * 8;
    if (t < 128) {
      const f32x4* xin = reinterpret_cast<const f32x4*>(x + (size_t)b0 * 64);
      reinterpret_cast<f32x4*>(&xs[0][0])[t] = xin[t];
    }
    __syncthreads();
    {  // t1[r][h] = elu(x @ f_fc1_w + b1), thread t = h
      float acc[8];
      float bias = b1[t];
#pragma unroll
      for (int r = 0; r < 8; ++r) acc[r] = bias;
      for (int n = 0; n < 64; ++n) {
        float w = w1[n * 256 + t];
#pragma unroll
        for (int r = 0; r < 8; ++r) acc[r] = fmaf(xs[r][n], w, acc[r]);
      }
#pragma unroll
      for (int r = 0; r < 8; ++r) {
        float z = acc[r];
        t1[r][t] = fmaxf(z, 0.f) + (__expf(fminf(z, 0.f)) - 1.f);
      }
    }
    __syncthreads();
    {  // h2 / skip / gate, thread = (nn = t&63, rg = t>>6), rows rg, rg+4
      const int nn = t & 63, rg = t >> 6;
      float a2[2], as_[2], ag[2];
      float bb2 = b2[nn], bbs = bsk[nn], bbg = bg[nn];
#pragma unroll
      for (int i = 0; i < 2; ++i) { a2[i] = bb2; as_[i] = bbs; ag[i] = bbg; }
      for (int h = 0; h < 256; ++h) {
        float w = w2[h * 64 + nn];
#pragma unroll
        for (int i = 0; i < 2; ++i) a2[i] = fmaf(t1[rg + 4 * i][h], w, a2[i]);
      }
      for (int m = 0; m < 64; ++m) {
        float ws_ = wsk[m * 64 + nn], wg_ = wg[m * 64 + nn];
#pragma unroll
        for (int i = 0; i < 2; ++i) {
          float xv = xs[rg + 4 * i][m];
          as_[i] = fmaf(xv, ws_, as_[i]);
          ag[i]  = fmaf(xv, wg_, ag[i]);
        }
      }
#pragma unroll
      for (int i = 0; i < 2; ++i) {
        float gt = __fdividef(1.f, 1.f + __expf(-ag[i]));
        wvv[rg + 4 * i][nn] = fmaf(gt, a2[i] - as_[i], as_[i]);
      }
    }
    __syncthreads();
    {  // LN over 64 + softmax over 64, wave handles 2 rows
      const int lane = t & 63, wid = t >> 6;
      float gl = lng[lane], bl = lnb[lane];
#pragma unroll
      for (int rr = 0; rr < 2; ++rr) {
        int r = wid * 2 + rr;
        float v = wvv[r][lane];
        float s = v;
        for (int m = 1; m < 64; m <<= 1) s += __shfl_xor(s, m);
        float mu = s * (1.f / 64.f);
        float d = v - mu;
        float q = d * d;
        for (int m = 1; m < 64; m <<= 1) q += __shfl_xor(q, m);
        float wn = d * rsqrtf(q * (1.f / 64.f) + 1e-5f) * gl + bl;
        float mx = wn;
        for (int m = 1; m < 64; m <<= 1) mx = fmaxf(mx, __shfl_xor(mx, m));
        float e = __expf(wn - mx);
        float se = e;
        for (int m = 1; m < 64; m <<= 1) se += __shfl_xor(se, m);
        spw[(size_t)(b0 + r) * 64 + lane] = __fdividef(e, se);
      }
    }
  }
}

// ---------------------------------------------------------------------------
// k2: fused einsum + gate/skip + LN(H) + weighted accumulate + FUSED split-k
// finisher (replaces the separate k3 reduction kernel).
// Main loop = R12 (one barrier per ni, proven 111.5us clean):
//   [zero sums ring -> issue W(ks0,1) -> pass2(ni-1) -> stage params(n+1)
//    -> ks-loop -> ep1+LDS atomics -> A-gen(ni+1) -> barrier]
// Tail: all 8 blocks of a btile store partials (nch0->comb, else slab),
// __threadfence (device scope, G16 cross-XCD pattern) -> per-btile counter
// atomicAdd; the 8th arriver acquires and sums the 8 partials in FIXED array
// order (deterministic regardless of arrival order; no spin -> no deadlock).
// (512,4) = 128-reg cap is the feasibility optimum (R7/R13 bracket).
// grid 1024: bid = btile*8 + nchunk; 512 thr / 8 waves; 2 blocks/CU; no tail.
// ---------------------------------------------------------------------------
template <bool ATOMIC>
__global__ __launch_bounds__(512, 4) void k2_main(
    const float* __restrict__ x,
    const ushort* __restrict__ w2p,
    const float* __restrict__ fc1w, const float* __restrict__ fc1b,
    const float* __restrict__ fc2b,
    const float* __restrict__ skw, const float* __restrict__ skb,
    const float* __restrict__ gww, const float* __restrict__ gwb,
    const float* __restrict__ lng, const float* __restrict__ lnb,
    const float* __restrict__ spw,
    float* __restrict__ comb, float* __restrict__ slabs,
    unsigned* __restrict__ cnt) {
  __shared__ __align__(16) char Ab[2][16384];   // act tiles 32x256 bf16, swizzled
  __shared__ __align__(16) float pbuf[3][1792]; // 7 param rows x 256, 3-ring
  __shared__ float xs[32][9];
  __shared__ float ss[32][9];
  __shared__ float sums[3][32][2];              // 3-ring
  __shared__ unsigned lastflag;

  const int bid = blockIdx.x;
  const int nch = bid & 7;
  const int b0  = (bid >> 3) * 32;
  const int t = threadIdx.x;
  const int lane = t & 63;
  const int w = t >> 6;          // 0..7 (32-col band)
  const int g = lane >> 4;
  const int cl = lane & 15;
  const int n0 = nch * 8;

  if (t < 256) {
    int r = t >> 3, j = t & 7;
    xs[r][j] = x[(size_t)(b0 + r) * 64 + nch * 8 + j];
    ss[r][j] = spw[(size_t)(b0 + r) * 64 + nch * 8 + j];
  }
  if (t < 64) (&sums[0][0][0])[t] = 0.f;   // slot 0 for ni=0

  // stage params(nn) -> pbuf[buf]: wave w<7 stages its array, 1 inst/wave
  auto STAGE = [&](int nn, int buf) {
    if (w < 7) {
      const float* ps;
      switch (w) {
        case 0: ps = fc2b; break;
        case 1: ps = skw;  break;
        case 2: ps = skb;  break;
        case 3: ps = gww;  break;
        case 4: ps = gwb;  break;
        case 5: ps = lng;  break;
        default: ps = lnb; break;
      }
      __builtin_amdgcn_global_load_lds(
          (const __attribute__((address_space(1))) unsigned int*)(ps + nn * 256 + lane * 4),
          (__attribute__((address_space(3))) unsigned int*)&pbuf[buf][w * 256],
          16, 0, 0);
    }
  };

  // A-gen: act[r][k] = elu(x[b0+r][nn]*fc1w[nn][k] + fc1b[nn][k]) -> abuf
  auto AGEN = [&](int nn, char* abuf) {
    const int kc = t & 31;
    const int rb = t >> 5;       // 0..15
    const int nloc = nn - n0;
    const float* w1p = fc1w + nn * 256 + kc * 8;
    const float* b1p = fc1b + nn * 256 + kc * 8;
    f32x4 wlo = *reinterpret_cast<const f32x4*>(w1p);
    f32x4 whi = *reinterpret_cast<const f32x4*>(w1p + 4);
    f32x4 blo = *reinterpret_cast<const f32x4*>(b1p);
    f32x4 bhi = *reinterpret_cast<const f32x4*>(b1p + 4);
#pragma unroll
    for (int i = 0; i < 2; ++i) {
      int r = rb + 16 * i;
      float xv = xs[r][nloc];
      s16x8 pk;
#pragma unroll
      for (int j = 0; j < 4; ++j) {
        float z0 = fmaf(xv, wlo[j], blo[j]);
        float z1 = fmaf(xv, whi[j], bhi[j]);
        float e0 = fmaxf(z0, 0.f) + (__expf(fminf(z0, 0.f)) - 1.f);
        float e1 = fmaxf(z1, 0.f) + (__expf(fminf(z1, 0.f)) - 1.f);
        __hip_bfloat16 h0 = __float2bfloat16(e0);
        __hip_bfloat16 h1 = __float2bfloat16(e1);
        pk[j]     = *reinterpret_cast<short*>(&h0);
        pk[j + 4] = *reinterpret_cast<short*>(&h1);
      }
      *reinterpret_cast<s16x8*>(abuf + r * 512 + ((kc << 4) ^ ((r & 7) << 4))) = pk;
    }
  };

  f32x4 comb_acc[2][2];
  f32x4 acc[2][2];               // live across the barrier into pass2
#pragma unroll
  for (int a = 0; a < 2; ++a)
#pragma unroll
    for (int b = 0; b < 2; ++b) comb_acc[a][b] = (f32x4){0.f, 0.f, 0.f, 0.f};

  // pass2 for n index pni: normalize + softmax-weighted accumulate
  auto PASS2 = [&](int pni) {
    const float* sb = &sums[pni % 3][0][0];
    const float* pb = &pbuf[pni % 3][0];
    float rsv[2], mrs[2], svv[2];
#pragma unroll
    for (int rt = 0; rt < 2; ++rt) {
      int row = rt * 16 + cl;
      float s0 = sb[row * 2], s1 = sb[row * 2 + 1];
      float mu = s0 * (1.f / 256.f);
      float rs = rsqrtf(fmaxf(s1 * (1.f / 256.f) - mu * mu, 0.f) + 1e-5f);
      rsv[rt] = rs;
      mrs[rt] = -mu * rs;
      svv[rt] = ss[row][pni];
    }
#pragma unroll
    for (int ct = 0; ct < 2; ++ct) {
      const int cl4 = (w * 2 + ct) * 16 + g * 4;
      f32x4 lg4 = *reinterpret_cast<const f32x4*>(pb + 5 * 256 + cl4);
      f32x4 lb4 = *reinterpret_cast<const f32x4*>(pb + 6 * 256 + cl4);
#pragma unroll
      for (int rt = 0; rt < 2; ++rt) {
#pragma unroll
        for (int j = 0; j < 4; ++j) {
          float tnorm = fmaf(acc[ct][rt][j], rsv[rt], mrs[rt]);
          float emb = fmaf(tnorm, lg4[j], lb4[j]);
          comb_acc[ct][rt][j] = fmaf(svv[rt], emb, comb_acc[ct][rt][j]);
        }
      }
    }
  };

  const s16x8* wf = reinterpret_cast<const s16x8*>(w2p);
#define BFRAG(nn, kk, ct) \
  (wf + (((size_t)((nn) * 8 + (kk)) * 16 + w * 2 + (ct)) * 64 + lane))

  __syncthreads();               // xs/ss (and sums slot 0) visible to ALL waves
  STAGE(n0, 0);                  // params(n0); drained by the barrier below
  AGEN(n0, Ab[0]);               // reads xs -- safe after the barrier above
  __syncthreads();               // Ab[0] ready; DMA drained

  for (int ni = 0; ni < 8; ++ni) {
    const int n = n0 + ni;
    // 1. rotate-zero sums slot for ni+1 (last read: pass2(ni-2), >=1 barrier ago)
    if (t < 64) (&sums[(ni + 1) % 3][0][0])[t] = 0.f;

    // 2. issue W prefetch ks=0,1 (latency covered by pass2 + stage below)
    s16x8 bfa[2], bfb[2];
#pragma unroll
    for (int ct = 0; ct < 2; ++ct) {
      bfa[ct] = *BFRAG(n, 0, ct);
      bfb[ct] = *BFRAG(n, 1, ct);
    }

    // 3. pass2 for previous n (reads sums/pbuf slot (ni-1)%3 + held acc)
    if (ni > 0) PASS2(ni - 1);

    // 4. stage params(n+1) into slot (ni+1)%3 (last read: ep1/pass2(ni-2))
    if (ni < 7) STAGE(n + 1, (ni + 1) % 3);

    // 5. K-loop: 8 ks, MFMA from Ab[ni&1] x W, rolling depth-2 prefetch
#pragma unroll
    for (int a = 0; a < 2; ++a)
#pragma unroll
      for (int b = 0; b < 2; ++b) acc[a][b] = (f32x4){0.f, 0.f, 0.f, 0.f};

    const char* abase = Ab[ni & 1];
#pragma unroll
    for (int ks = 0; ks < 8; ++ks) {
      s16x8* cur = (ks & 1) ? bfb : bfa;
      s16x8 af[2];
#pragma unroll
      for (int rt = 0; rt < 2; ++rt) {
        int row = rt * 16 + cl;
        af[rt] = *reinterpret_cast<const s16x8*>(
            abase + row * 512 + (((ks * 4 + g) << 4) ^ ((row & 7) << 4)));
      }
#pragma unroll
      for (int ct = 0; ct < 2; ++ct)
#pragma unroll
        for (int rt = 0; rt < 2; ++rt)
          acc[ct][rt] = __builtin_amdgcn_mfma_f32_16x16x32_bf16(
              cur[ct], af[rt], acc[ct][rt], 0, 0, 0);
      if (ks < 6) {
#pragma unroll
        for (int ct = 0; ct < 2; ++ct) cur[ct] = *BFRAG(n, ks + 2, ct);
      }
    }

    // 6. ep1: gate mix + lane-local row stats -> sums[ni%3]
    {
      const float* pb = &pbuf[ni % 3][0];
      float xr[2], rsum[2], rsq[2];
#pragma unroll
      for (int rt = 0; rt < 2; ++rt) {
        xr[rt] = xs[rt * 16 + cl][ni];
        rsum[rt] = 0.f;
        rsq[rt] = 0.f;
      }
#pragma unroll
      for (int ct = 0; ct < 2; ++ct) {
        const int cl4 = (w * 2 + ct) * 16 + g * 4;
        f32x4 f2b4 = *reinterpret_cast<const f32x4*>(pb + 0 * 256 + cl4);
        f32x4 sw4  = *reinterpret_cast<const f32x4*>(pb + 1 * 256 + cl4);
        f32x4 sb4  = *reinterpret_cast<const f32x4*>(pb + 2 * 256 + cl4);
        f32x4 gw4  = *reinterpret_cast<const f32x4*>(pb + 3 * 256 + cl4);
        f32x4 gb4  = *reinterpret_cast<const f32x4*>(pb + 4 * 256 + cl4);
#pragma unroll
        for (int rt = 0; rt < 2; ++rt) {
#pragma unroll
          for (int j = 0; j < 4; ++j) {
            float hv = acc[ct][rt][j] + f2b4[j];
            float sk = fmaf(xr[rt], sw4[j], sb4[j]);
            float gv = __fdividef(1.f, 1.f + __expf(-fmaf(xr[rt], gw4[j], gb4[j])));
            float p = fmaf(gv, hv - sk, sk);
            acc[ct][rt][j] = p;
            rsum[rt] += p;
            rsq[rt] = fmaf(p, p, rsq[rt]);
          }
        }
      }
#pragma unroll
      for (int rt = 0; rt < 2; ++rt) {
        rsum[rt] += __shfl_xor(rsum[rt], 16);
        rsum[rt] += __shfl_xor(rsum[rt], 32);
        rsq[rt]  += __shfl_xor(rsq[rt], 16);
        rsq[rt]  += __shfl_xor(rsq[rt], 32);
      }
      if (g == 0) {
        float* sb2 = &sums[ni % 3][0][0];
#pragma unroll
        for (int rt = 0; rt < 2; ++rt) {
          atomicAdd(&sb2[(rt * 16 + cl) * 2 + 0], rsum[rt]);
          atomicAdd(&sb2[(rt * 16 + cl) * 2 + 1], rsq[rt]);
        }
      }
    }

    // 7. A-gen(ni+1) into the other Ab buffer (drains the atomics)
    if (ni < 7) AGEN(n + 1, Ab[(ni + 1) & 1]);

    // 8. the ONLY barrier of the iteration
    __syncthreads();
  }

  PASS2(7);
#undef BFRAG

  // ---- store partial ----
  float* outp;
  if (ATOMIC) outp = comb;
  else outp = (nch == 0) ? comb : slabs + (size_t)(nch - 1) * SLAB_FLOATS;
#pragma unroll
  for (int ct = 0; ct < 2; ++ct)
#pragma unroll
    for (int rt = 0; rt < 2; ++rt) {
      size_t idx = (size_t)(b0 + rt * 16 + cl) * 256 + (w * 2 + ct) * 16 + g * 4;
      if (ATOMIC) {
#pragma unroll
        for (int j = 0; j < 4; ++j)
          atomicAdd(&outp[idx + j], comb_acc[ct][rt][j]);
      } else {
        *reinterpret_cast<f32x4*>(outp + idx) = comb_acc[ct][rt];
      }
    }

  // ---- fused split-k finisher: 8th arriver of this btile reduces ----
  if (!ATOMIC) {
    __threadfence();             // release: partial stores visible device-wide
    __syncthreads();             // all threads' fences complete
    if (t == 0) lastflag = atomicAdd(&cnt[bid >> 3], 1u);
    __syncthreads();
    if (lastflag == 7) {         // this block arrived last: all 8 partials stored
      __threadfence();           // acquire
      f32x4* comb4 = reinterpret_cast<f32x4*>(comb);
      const f32x4* slab4 = reinterpret_cast<const f32x4*>(slabs);
      const size_t base = (size_t)b0 * 64;   // b0*256/4 f32x4 per row-slice
#pragma unroll
      for (int q = 0; q < 4; ++q) {
        size_t i = base + q * 512 + t;
        f32x4 v = comb4[i];
#pragma unroll
        for (int s = 0; s < 7; ++s)
          v += slab4[(size_t)s * (SLAB_FLOATS / 4) + i];
        comb4[i] = v;
      }
    }
  }
}

// ---------------------------------------------------------------------------
extern "C" void kernel_launch(void* const* d_in, const int* in_sizes, int n_in,
                              void* d_out, int out_size, void* d_ws, size_t ws_size,
                              hipStream_t stream) {
  const float* x   = (const float*)d_in[0];
  const float* f1w = (const float*)d_in[1];
  const float* f1b = (const float*)d_in[2];
  const float* f2w = (const float*)d_in[3];
  const float* f2b = (const float*)d_in[4];
  const float* fsw = (const float*)d_in[5];
  const float* fsb = (const float*)d_in[6];
  const float* fgw = (const float*)d_in[7];
  const float* fgb = (const float*)d_in[8];
  const float* flg = (const float*)d_in[9];
  const float* flb = (const float*)d_in[10];
  const float* g1w = (const float*)d_in[11];
  const float* g1b = (const float*)d_in[12];
  const float* g2w = (const float*)d_in[13];
  const float* g2b = (const float*)d_in[14];
  const float* gsw = (const float*)d_in[15];
  const float* gsb = (const float*)d_in[16];
  const float* ggw = (const float*)d_in[17];
  const float* ggb = (const float*)d_in[18];
  const float* glg = (const float*)d_in[19];
  const float* glb = (const float*)d_in[20];

  float* out  = (float*)d_out;
  float* comb = out;                          // (4096,256)
  float* spw  = out + (size_t)4096 * 256;     // (4096,64)
  ushort* w2p = (ushort*)d_ws;                // 8.4 MB packed bf16 W-frags
  float* slabs = (float*)((char*)d_ws + W2P_BYTES);   // 7 x 4 MB partials
  unsigned* cnt = (unsigned*)((char*)d_ws + CNT_OFF); // 128 btile counters

  k01<<<1024, 256, 0, stream>>>(g2w, w2p, x, f1w, f1b, f2w, f2b,
                                fsw, fsb, fgw, fgb, flg, flb, spw);
  if (ws_size >= WS_NEEDED) {
    hipMemsetAsync(cnt, 0, 512, stream);      // reset finisher counters
    k2_main<false><<<1024, 512, 0, stream>>>(x, w2p, g1w, g1b, g2b, gsw, gsb,
                                             ggw, ggb, glg, glb, spw, comb,
                                             slabs, cnt);
  } else {
    hipMemsetAsync(comb, 0, (size_t)4096 * 256 * sizeof(float), stream);
    k2_main<true><<<1024, 512, 0, stream>>>(x, w2p, g1w, g1b, g2b, gsw, gsb,
                                            ggw, ggb, glg, glb, spw, comb,
                                            slabs, cnt);
  }
}

// Round 16
// 129.642 us; speedup vs baseline: 4.2035x; 4.2035x over previous
//
#include <hip/hip_runtime.h>
#include <hip/hip_bf16.h>

typedef __attribute__((ext_vector_type(4))) float f32x4;
typedef __attribute__((ext_vector_type(8))) short s16x8;

#define W2P_BYTES   8388608ull                 // 64*256*256 bf16
#define SLAB_FLOATS 1048576ull                 // 4096*256
#define WS_NEEDED   (W2P_BYTES + 7ull * SLAB_FLOATS * 4ull)

// ---------------------------------------------------------------------------
// k01: fused weight-pack (blocks 0..511) + f-path select (blocks 512..1023).
// Disjoint block ranges, shared LDS buffer, zero interaction.
// pack: g_fc2_w (64,256,256) fp32 -> bf16 MFMA fragments, 1KB contiguous per
// fragment; frag f = (n*8+ks)*16 + ct: lane l, elem j =
//   g2w[n][ks*32 + (l>>4)*8 + j][ct*16 + (l&15)]
// select: sparse_w (4096,64), 8 rows per block.
// ---------------------------------------------------------------------------
__global__ __launch_bounds__(256) void k01(
    const float* __restrict__ g2w, ushort* __restrict__ out,
    const float* __restrict__ x,
    const float* __restrict__ w1, const float* __restrict__ b1,
    const float* __restrict__ w2, const float* __restrict__ b2,
    const float* __restrict__ wsk, const float* __restrict__ bsk,
    const float* __restrict__ wg, const float* __restrict__ bg,
    const float* __restrict__ lng, const float* __restrict__ lnb,
    float* __restrict__ spw) {
  __shared__ __align__(16) float shbuf[32 * 257];
  const int t = threadIdx.x;
  if (blockIdx.x < 512) {
    // ---------------- pack path ----------------
    float (*tile)[257] = reinterpret_cast<float (*)[257]>(shbuf);
    const int n = blockIdx.x >> 3, ks = blockIdx.x & 7;
    const float* src = g2w + ((size_t)n * 256 + ks * 32) * 256;
    for (int i = t; i < 8192; i += 256)
      tile[i >> 8][i & 255] = src[i];
    __syncthreads();
#pragma unroll
    for (int q = 0; q < 4; ++q) {
      int chunk = q * 256 + t;
      int ct = chunk >> 6, l = chunk & 63;
      int g = l >> 4, cl = l & 15;
      s16x8 pk;
#pragma unroll
      for (int j = 0; j < 8; ++j) {
        __hip_bfloat16 h = __float2bfloat16(tile[g * 8 + j][ct * 16 + cl]);
        pk[j] = *reinterpret_cast<short*>(&h);
      }
      *reinterpret_cast<s16x8*>(out + ((size_t)(n * 8 + ks) * 1024 + chunk) * 8) = pk;
    }
  } else {
    // ---------------- select path ----------------
    float (*xs)[64]  = reinterpret_cast<float (*)[64]>(shbuf);
    float (*t1)[256] = reinterpret_cast<float (*)[256]>(shbuf + 512);
    float (*wvv)[64] = reinterpret_cast<float (*)[64]>(shbuf + 2560);
    const int b0 = (int)(blockIdx.x - 512) * 8;
    if (t < 128) {
      const f32x4* xin = reinterpret_cast<const f32x4*>(x + (size_t)b0 * 64);
      reinterpret_cast<f32x4*>(&xs[0][0])[t] = xin[t];
    }
    __syncthreads();
    {  // t1[r][h] = elu(x @ f_fc1_w + b1), thread t = h
      float acc[8];
      float bias = b1[t];
#pragma unroll
      for (int r = 0; r < 8; ++r) acc[r] = bias;
      for (int n = 0; n < 64; ++n) {
        float w = w1[n * 256 + t];
#pragma unroll
        for (int r = 0; r < 8; ++r) acc[r] = fmaf(xs[r][n], w, acc[r]);
      }
#pragma unroll
      for (int r = 0; r < 8; ++r) {
        float z = acc[r];
        t1[r][t] = fmaxf(z, 0.f) + (__expf(fminf(z, 0.f)) - 1.f);
      }
    }
    __syncthreads();
    {  // h2 / skip / gate, thread = (nn = t&63, rg = t>>6), rows rg, rg+4
      const int nn = t & 63, rg = t >> 6;
      float a2[2], as_[2], ag[2];
      float bb2 = b2[nn], bbs = bsk[nn], bbg = bg[nn];
#pragma unroll
      for (int i = 0; i < 2; ++i) { a2[i] = bb2; as_[i] = bbs; ag[i] = bbg; }
      for (int h = 0; h < 256; ++h) {
        float w = w2[h * 64 + nn];
#pragma unroll
        for (int i = 0; i < 2; ++i) a2[i] = fmaf(t1[rg + 4 * i][h], w, a2[i]);
      }
      for (int m = 0; m < 64; ++m) {
        float ws_ = wsk[m * 64 + nn], wg_ = wg[m * 64 + nn];
#pragma unroll
        for (int i = 0; i < 2; ++i) {
          float xv = xs[rg + 4 * i][m];
          as_[i] = fmaf(xv, ws_, as_[i]);
          ag[i]  = fmaf(xv, wg_, ag[i]);
        }
      }
#pragma unroll
      for (int i = 0; i < 2; ++i) {
        float gt = __fdividef(1.f, 1.f + __expf(-ag[i]));
        wvv[rg + 4 * i][nn] = fmaf(gt, a2[i] - as_[i], as_[i]);
      }
    }
    __syncthreads();
    {  // LN over 64 + softmax over 64, wave handles 2 rows
      const int lane = t & 63, wid = t >> 6;
      float gl = lng[lane], bl = lnb[lane];
#pragma unroll
      for (int rr = 0; rr < 2; ++rr) {
        int r = wid * 2 + rr;
        float v = wvv[r][lane];
        float s = v;
        for (int m = 1; m < 64; m <<= 1) s += __shfl_xor(s, m);
        float mu = s * (1.f / 64.f);
        float d = v - mu;
        float q = d * d;
        for (int m = 1; m < 64; m <<= 1) q += __shfl_xor(q, m);
        float wn = d * rsqrtf(q * (1.f / 64.f) + 1e-5f) * gl + bl;
        float mx = wn;
        for (int m = 1; m < 64; m <<= 1) mx = fmaxf(mx, __shfl_xor(mx, m));
        float e = __expf(wn - mx);
        float se = e;
        for (int m = 1; m < 64; m <<= 1) se += __shfl_xor(se, m);
        spw[(size_t)(b0 + r) * 64 + lane] = __fdividef(e, se);
      }
    }
  }
}

// ---------------------------------------------------------------------------
// k2: fused einsum + gate/skip + LN(H) + weighted accumulate.  (R12 final)
// ONE barrier per ni; prologue barrier before AGEN(n0).
// Iteration: [zero sums ring -> issue W(ks0,1) -> pass2(ni-1) ->
//   stage params(n+1) -> ks-loop -> ep1+LDS atomics -> A-gen(ni+1) -> barrier]
// Ab double-buffered; pbuf/sums 3-rings (every slot write >=1 barrier after
// its last reader).  Only acc+comb_acc live across the barrier; W prefetch
// depth-2 within-n.  (512,4) = 128-reg cap is the feasibility optimum:
// (256,3)/168 regs = latency-starved (R7); (512,6)/80 regs = spill (R13);
// fused cross-XCD finisher with per-block __threadfence = L2-flush storm (R15).
// grid 1024: bid = btile*8 + nchunk; 512 thr / 8 waves; 2 blocks/CU; no tail.
// ---------------------------------------------------------------------------
template <bool ATOMIC>
__global__ __launch_bounds__(512, 4) void k2_main(
    const float* __restrict__ x,
    const ushort* __restrict__ w2p,
    const float* __restrict__ fc1w, const float* __restrict__ fc1b,
    const float* __restrict__ fc2b,
    const float* __restrict__ skw, const float* __restrict__ skb,
    const float* __restrict__ gww, const float* __restrict__ gwb,
    const float* __restrict__ lng, const float* __restrict__ lnb,
    const float* __restrict__ spw,
    float* __restrict__ comb, float* __restrict__ slabs) {
  __shared__ __align__(16) char Ab[2][16384];   // act tiles 32x256 bf16, swizzled
  __shared__ __align__(16) float pbuf[3][1792]; // 7 param rows x 256, 3-ring
  __shared__ float xs[32][9];
  __shared__ float ss[32][9];
  __shared__ float sums[3][32][2];              // 3-ring

  const int bid = blockIdx.x;
  const int nch = bid & 7;
  const int b0  = (bid >> 3) * 32;
  const int t = threadIdx.x;
  const int lane = t & 63;
  const int w = t >> 6;          // 0..7 (32-col band)
  const int g = lane >> 4;
  const int cl = lane & 15;
  const int n0 = nch * 8;

  if (t < 256) {
    int r = t >> 3, j = t & 7;
    xs[r][j] = x[(size_t)(b0 + r) * 64 + nch * 8 + j];
    ss[r][j] = spw[(size_t)(b0 + r) * 64 + nch * 8 + j];
  }
  if (t < 64) (&sums[0][0][0])[t] = 0.f;   // slot 0 for ni=0

  // stage params(nn) -> pbuf[buf]: wave w<7 stages its array, 1 inst/wave
  auto STAGE = [&](int nn, int buf) {
    if (w < 7) {
      const float* ps;
      switch (w) {
        case 0: ps = fc2b; break;
        case 1: ps = skw;  break;
        case 2: ps = skb;  break;
        case 3: ps = gww;  break;
        case 4: ps = gwb;  break;
        case 5: ps = lng;  break;
        default: ps = lnb; break;
      }
      __builtin_amdgcn_global_load_lds(
          (const __attribute__((address_space(1))) unsigned int*)(ps + nn * 256 + lane * 4),
          (__attribute__((address_space(3))) unsigned int*)&pbuf[buf][w * 256],
          16, 0, 0);
    }
  };

  // A-gen: act[r][k] = elu(x[b0+r][nn]*fc1w[nn][k] + fc1b[nn][k]) -> abuf
  auto AGEN = [&](int nn, char* abuf) {
    const int kc = t & 31;
    const int rb = t >> 5;       // 0..15
    const int nloc = nn - n0;
    const float* w1p = fc1w + nn * 256 + kc * 8;
    const float* b1p = fc1b + nn * 256 + kc * 8;
    f32x4 wlo = *reinterpret_cast<const f32x4*>(w1p);
    f32x4 whi = *reinterpret_cast<const f32x4*>(w1p + 4);
    f32x4 blo = *reinterpret_cast<const f32x4*>(b1p);
    f32x4 bhi = *reinterpret_cast<const f32x4*>(b1p + 4);
#pragma unroll
    for (int i = 0; i < 2; ++i) {
      int r = rb + 16 * i;
      float xv = xs[r][nloc];
      s16x8 pk;
#pragma unroll
      for (int j = 0; j < 4; ++j) {
        float z0 = fmaf(xv, wlo[j], blo[j]);
        float z1 = fmaf(xv, whi[j], bhi[j]);
        float e0 = fmaxf(z0, 0.f) + (__expf(fminf(z0, 0.f)) - 1.f);
        float e1 = fmaxf(z1, 0.f) + (__expf(fminf(z1, 0.f)) - 1.f);
        __hip_bfloat16 h0 = __float2bfloat16(e0);
        __hip_bfloat16 h1 = __float2bfloat16(e1);
        pk[j]     = *reinterpret_cast<short*>(&h0);
        pk[j + 4] = *reinterpret_cast<short*>(&h1);
      }
      *reinterpret_cast<s16x8*>(abuf + r * 512 + ((kc << 4) ^ ((r & 7) << 4))) = pk;
    }
  };

  f32x4 comb_acc[2][2];
  f32x4 acc[2][2];               // live across the barrier into pass2
#pragma unroll
  for (int a = 0; a < 2; ++a)
#pragma unroll
    for (int b = 0; b < 2; ++b) comb_acc[a][b] = (f32x4){0.f, 0.f, 0.f, 0.f};

  // pass2 for n index pni: normalize + softmax-weighted accumulate
  auto PASS2 = [&](int pni) {
    const float* sb = &sums[pni % 3][0][0];
    const float* pb = &pbuf[pni % 3][0];
    float rsv[2], mrs[2], svv[2];
#pragma unroll
    for (int rt = 0; rt < 2; ++rt) {
      int row = rt * 16 + cl;
      float s0 = sb[row * 2], s1 = sb[row * 2 + 1];
      float mu = s0 * (1.f / 256.f);
      float rs = rsqrtf(fmaxf(s1 * (1.f / 256.f) - mu * mu, 0.f) + 1e-5f);
      rsv[rt] = rs;
      mrs[rt] = -mu * rs;
      svv[rt] = ss[row][pni];
    }
#pragma unroll
    for (int ct = 0; ct < 2; ++ct) {
      const int cl4 = (w * 2 + ct) * 16 + g * 4;
      f32x4 lg4 = *reinterpret_cast<const f32x4*>(pb + 5 * 256 + cl4);
      f32x4 lb4 = *reinterpret_cast<const f32x4*>(pb + 6 * 256 + cl4);
#pragma unroll
      for (int rt = 0; rt < 2; ++rt) {
#pragma unroll
        for (int j = 0; j < 4; ++j) {
          float tnorm = fmaf(acc[ct][rt][j], rsv[rt], mrs[rt]);
          float emb = fmaf(tnorm, lg4[j], lb4[j]);
          comb_acc[ct][rt][j] = fmaf(svv[rt], emb, comb_acc[ct][rt][j]);
        }
      }
    }
  };

  const s16x8* wf = reinterpret_cast<const s16x8*>(w2p);
#define BFRAG(nn, kk, ct) \
  (wf + (((size_t)((nn) * 8 + (kk)) * 16 + w * 2 + (ct)) * 64 + lane))

  __syncthreads();               // xs/ss (and sums slot 0) visible to ALL waves
  STAGE(n0, 0);                  // params(n0); drained by the barrier below
  AGEN(n0, Ab[0]);               // reads xs -- safe after the barrier above
  __syncthreads();               // Ab[0] ready; DMA drained

  for (int ni = 0; ni < 8; ++ni) {
    const int n = n0 + ni;
    // 1. rotate-zero sums slot for ni+1 (last read: pass2(ni-2), >=1 barrier ago)
    if (t < 64) (&sums[(ni + 1) % 3][0][0])[t] = 0.f;

    // 2. issue W prefetch ks=0,1 (latency covered by pass2 + stage below)
    s16x8 bfa[2], bfb[2];
#pragma unroll
    for (int ct = 0; ct < 2; ++ct) {
      bfa[ct] = *BFRAG(n, 0, ct);
      bfb[ct] = *BFRAG(n, 1, ct);
    }

    // 3. pass2 for previous n (reads sums/pbuf slot (ni-1)%3 + held acc)
    if (ni > 0) PASS2(ni - 1);

    // 4. stage params(n+1) into slot (ni+1)%3 (last read: ep1/pass2(ni-2))
    if (ni < 7) STAGE(n + 1, (ni + 1) % 3);

    // 5. K-loop: 8 ks, MFMA from Ab[ni&1] x W, rolling depth-2 prefetch
#pragma unroll
    for (int a = 0; a < 2; ++a)
#pragma unroll
      for (int b = 0; b < 2; ++b) acc[a][b] = (f32x4){0.f, 0.f, 0.f, 0.f};

    const char* abase = Ab[ni & 1];
#pragma unroll
    for (int ks = 0; ks < 8; ++ks) {
      s16x8* cur = (ks & 1) ? bfb : bfa;
      s16x8 af[2];
#pragma unroll
      for (int rt = 0; rt < 2; ++rt) {
        int row = rt * 16 + cl;
        af[rt] = *reinterpret_cast<const s16x8*>(
            abase + row * 512 + (((ks * 4 + g) << 4) ^ ((row & 7) << 4)));
      }
#pragma unroll
      for (int ct = 0; ct < 2; ++ct)
#pragma unroll
        for (int rt = 0; rt < 2; ++rt)
          acc[ct][rt] = __builtin_amdgcn_mfma_f32_16x16x32_bf16(
              cur[ct], af[rt], acc[ct][rt], 0, 0, 0);
      if (ks < 6) {
#pragma unroll
        for (int ct = 0; ct < 2; ++ct) cur[ct] = *BFRAG(n, ks + 2, ct);
      }
    }

    // 6. ep1: gate mix + lane-local row stats -> sums[ni%3]
    {
      const float* pb = &pbuf[ni % 3][0];
      float xr[2], rsum[2], rsq[2];
#pragma unroll
      for (int rt = 0; rt < 2; ++rt) {
        xr[rt] = xs[rt * 16 + cl][ni];
        rsum[rt] = 0.f;
        rsq[rt] = 0.f;
      }
#pragma unroll
      for (int ct = 0; ct < 2; ++ct) {
        const int cl4 = (w * 2 + ct) * 16 + g * 4;
        f32x4 f2b4 = *reinterpret_cast<const f32x4*>(pb + 0 * 256 + cl4);
        f32x4 sw4  = *reinterpret_cast<const f32x4*>(pb + 1 * 256 + cl4);
        f32x4 sb4  = *reinterpret_cast<const f32x4*>(pb + 2 * 256 + cl4);
        f32x4 gw4  = *reinterpret_cast<const f32x4*>(pb + 3 * 256 + cl4);
        f32x4 gb4  = *reinterpret_cast<const f32x4*>(pb + 4 * 256 + cl4);
#pragma unroll
        for (int rt = 0; rt < 2; ++rt) {
#pragma unroll
          for (int j = 0; j < 4; ++j) {
            float hv = acc[ct][rt][j] + f2b4[j];
            float sk = fmaf(xr[rt], sw4[j], sb4[j]);
            float gv = __fdividef(1.f, 1.f + __expf(-fmaf(xr[rt], gw4[j], gb4[j])));
            float p = fmaf(gv, hv - sk, sk);
            acc[ct][rt][j] = p;
            rsum[rt] += p;
            rsq[rt] = fmaf(p, p, rsq[rt]);
          }
        }
      }
#pragma unroll
      for (int rt = 0; rt < 2; ++rt) {
        rsum[rt] += __shfl_xor(rsum[rt], 16);
        rsum[rt] += __shfl_xor(rsum[rt], 32);
        rsq[rt]  += __shfl_xor(rsq[rt], 16);
        rsq[rt]  += __shfl_xor(rsq[rt], 32);
      }
      if (g == 0) {
        float* sb2 = &sums[ni % 3][0][0];
#pragma unroll
        for (int rt = 0; rt < 2; ++rt) {
          atomicAdd(&sb2[(rt * 16 + cl) * 2 + 0], rsum[rt]);
          atomicAdd(&sb2[(rt * 16 + cl) * 2 + 1], rsq[rt]);
        }
      }
    }

    // 7. A-gen(ni+1) into the other Ab buffer (drains the atomics)
    if (ni < 7) AGEN(n + 1, Ab[(ni + 1) & 1]);

    // 8. the ONLY barrier of the iteration
    __syncthreads();
  }

  PASS2(7);
#undef BFRAG

  float* outp;
  if (ATOMIC) outp = comb;
  else outp = (nch == 0) ? comb : slabs + (size_t)(nch - 1) * SLAB_FLOATS;
#pragma unroll
  for (int ct = 0; ct < 2; ++ct)
#pragma unroll
    for (int rt = 0; rt < 2; ++rt) {
      size_t idx = (size_t)(b0 + rt * 16 + cl) * 256 + (w * 2 + ct) * 16 + g * 4;
      if (ATOMIC) {
#pragma unroll
        for (int j = 0; j < 4; ++j)
          atomicAdd(&outp[idx + j], comb_acc[ct][rt][j]);
      } else {
        *reinterpret_cast<f32x4*>(outp + idx) = comb_acc[ct][rt];
      }
    }
}

// ---------------------------------------------------------------------------
// k3: comb += sum of the 7 partial slabs.  grid 1024 x 256, f32x4 per thread.
// (Separate kernel on purpose: cross-XCD visibility is provided by the
// kernel boundary -- one implicit flush -- instead of per-block fences.)
// ---------------------------------------------------------------------------
__global__ __launch_bounds__(256) void k3_reduce(float* __restrict__ comb,
                                                 const float* __restrict__ slabs) {
  size_t i = (size_t)blockIdx.x * 256 + threadIdx.x;   // f32x4 index
  f32x4 v = reinterpret_cast<const f32x4*>(comb)[i];
#pragma unroll
  for (int s = 0; s < 7; ++s)
    v += reinterpret_cast<const f32x4*>(slabs)[s * (SLAB_FLOATS / 4) + i];
  reinterpret_cast<f32x4*>(comb)[i] = v;
}

// ---------------------------------------------------------------------------
extern "C" void kernel_launch(void* const* d_in, const int* in_sizes, int n_in,
                              void* d_out, int out_size, void* d_ws, size_t ws_size,
                              hipStream_t stream) {
  const float* x   = (const float*)d_in[0];
  const float* f1w = (const float*)d_in[1];
  const float* f1b = (const float*)d_in[2];
  const float* f2w = (const float*)d_in[3];
  const float* f2b = (const float*)d_in[4];
  const float* fsw = (const float*)d_in[5];
  const float* fsb = (const float*)d_in[6];
  const float* fgw = (const float*)d_in[7];
  const float* fgb = (const float*)d_in[8];
  const float* flg = (const float*)d_in[9];
  const float* flb = (const float*)d_in[10];
  const float* g1w = (const float*)d_in[11];
  const float* g1b = (const float*)d_in[12];
  const float* g2w = (const float*)d_in[13];
  const float* g2b = (const float*)d_in[14];
  const float* gsw = (const float*)d_in[15];
  const float* gsb = (const float*)d_in[16];
  const float* ggw = (const float*)d_in[17];
  const float* ggb = (const float*)d_in[18];
  const float* glg = (const float*)d_in[19];
  const float* glb = (const float*)d_in[20];

  float* out  = (float*)d_out;
  float* comb = out;                          // (4096,256)
  float* spw  = out + (size_t)4096 * 256;     // (4096,64)
  ushort* w2p = (ushort*)d_ws;                // 8.4 MB packed bf16 W-frags
  float* slabs = (float*)((char*)d_ws + W2P_BYTES);  // 7 x 4 MB partials

  k01<<<1024, 256, 0, stream>>>(g2w, w2p, x, f1w, f1b, f2w, f2b,
                                fsw, fsb, fgw, fgb, flg, flb, spw);
  if (ws_size >= WS_NEEDED) {
    k2_main<false><<<1024, 512, 0, stream>>>(x, w2p, g1w, g1b, g2b, gsw, gsb,
                                             ggw, ggb, glg, glb, spw, comb, slabs);
    k3_reduce<<<1024, 256, 0, stream>>>(comb, slabs);
  } else {
    hipMemsetAsync(comb, 0, (size_t)4096 * 256 * sizeof(float), stream);
    k2_main<true><<<1024, 512, 0, stream>>>(x, w2p, g1w, g1b, g2b, gsw, gsb,
                                            ggw, ggb, glg, glb, spw, comb, slabs);
  }
}